// Round 17
// baseline (192.325 us; speedup 1.0000x reference)
//
#include <hip/hip_runtime.h>
#include <hip/hip_bf16.h>
#include <stdint.h>

#define NROWS 8192
#define DIM   256
#define KDIM  512          // H*D concatenated
#define THRESH 0.2f
#define MARGIN 0.005f      // hard bound on |bf16-gemm val - f64 true sim|
#define BLK_FIX_CAP 512    // ~23 expected candidates per 128x128 block
#define TOPK_CAP 4096
#define NTILE 2080         // 64*65/2 upper-tri tiles
#define GRID_P 1040        // persistent grid: each block does u and u+GRID_P

typedef __bf16 bf16x8 __attribute__((ext_vector_type(8)));
typedef float  f32x4  __attribute__((ext_vector_type(4)));
typedef float  f32x2  __attribute__((ext_vector_type(2)));

__device__ __forceinline__ void gload16(const void* g, void* l) {
  __builtin_amdgcn_global_load_lds(
      (const __attribute__((address_space(1))) uint32_t*)g,
      (__attribute__((address_space(3))) uint32_t*)l,
      16, 0, 0);
}

// Triangular decode: tile u -> (bm, bn), bm<=bn, T(bm)=bm*(129-bm)/2.
__device__ __forceinline__ void tri_decode(int u, int& bm, int& bn) {
  bm = (int)((129.0 - sqrt(129.0 * 129.0 - 8.0 * (double)u)) * 0.5);
  if (bm > 63) bm = 63;
  while (bm * (129 - bm) / 2 > u) --bm;
  while ((bm + 1) * (129 - (bm + 1)) / 2 <= u) ++bm;
  bn = bm + (u - bm * (129 - bm) / 2);
}

// ---------------- Pass 1: z[n][512] = concat_h( (x*w_h)/max(||x*w_h||,eps) ) / sqrt(2), bf16.
// One wave per row (4 rows/block): float4 loads, butterfly reduce, no LDS/sync.
// Also zeroes cnt (folded memset).
__global__ __launch_bounds__(256) void prep_k(const float* __restrict__ x,
                                              const float* __restrict__ w,
                                              ushort* __restrict__ z,
                                              int* __restrict__ cnt) {
  const int wv = threadIdx.x >> 6, lane = threadIdx.x & 63;
  const int n = blockIdx.x * 4 + wv;
  if (lane == 0) cnt[n] = 0;
  const int d4 = lane * 4;
  const f32x4 xv = *(const f32x4*)&x[(size_t)n * DIM + d4];
  const f32x4 w0 = *(const f32x4*)&w[d4];
  const f32x4 w1 = *(const f32x4*)&w[DIM + d4];
  f32x4 p0, p1;
  float s0 = 0.f, s1 = 0.f;
  #pragma unroll
  for (int j = 0; j < 4; ++j) {
    p0[j] = xv[j] * w0[j];  s0 += p0[j] * p0[j];
    p1[j] = xv[j] * w1[j];  s1 += p1[j] * p1[j];
  }
  #pragma unroll
  for (int off = 32; off > 0; off >>= 1) {
    s0 += __shfl_xor(s0, off);
    s1 += __shfl_xor(s1, off);
  }
  const float inv0 = 0.70710678118654752f / fmaxf(sqrtf(s0), 1e-8f);
  const float inv1 = 0.70710678118654752f / fmaxf(sqrtf(s1), 1e-8f);
  ushort4 o0, o1;
  {
    __hip_bfloat16 b;
    b = __float2bfloat16(p0[0] * inv0); o0.x = *(ushort*)&b;
    b = __float2bfloat16(p0[1] * inv0); o0.y = *(ushort*)&b;
    b = __float2bfloat16(p0[2] * inv0); o0.z = *(ushort*)&b;
    b = __float2bfloat16(p0[3] * inv0); o0.w = *(ushort*)&b;
    b = __float2bfloat16(p1[0] * inv1); o1.x = *(ushort*)&b;
    b = __float2bfloat16(p1[1] * inv1); o1.y = *(ushort*)&b;
    b = __float2bfloat16(p1[2] * inv1); o1.z = *(ushort*)&b;
    b = __float2bfloat16(p1[3] * inv1); o1.w = *(ushort*)&b;
  }
  *(ushort4*)&z[(size_t)n * KDIM + d4]       = o0;
  *(ushort4*)&z[(size_t)n * KDIM + DIM + d4] = o1;
}

// ---------------- Pass 2: persistent blocks — each processes 2 upper-tri tiles.
// Per tile: counted-vmcnt 2-deep K-loop; dense epilogue (plain direct stores +
// LDS-transposed nt mirror); fused f64 fixup. Tile 1's prologue staging is issued
// under tile 0's fixup (post-drain) to hide the staging latency.
__global__ __launch_bounds__(256, 4) void sim_gemm(const ushort* __restrict__ z,
                                               const float* __restrict__ x,
                                               const float* __restrict__ w,
                                               float* __restrict__ out,
                                               int* __restrict__ cnt) {
  __shared__ __align__(16) char smem[33280];
  ushort* ASb = (ushort*)smem;               // ASb + b*4096 : A stage buffer b
  ushort* BSb = (ushort*)(smem + 16384);     // BSb + b*4096 : B stage buffer b
  auto T2 = (float (*)[32][130])smem;        // alias, post-K-loop only
  __shared__ int cntA[128], cntB[128];
  __shared__ uint32_t fix_loc[BLK_FIX_CAP];
  __shared__ int fix_loc_n;

  const int t = threadIdx.x;
  const int wv = t >> 6, lane = t & 63;
  const int wr = wv >> 1, wc = wv & 1;

  // Per-thread staging slot (tile-independent).
  const int i0 = t, r0 = i0 >> 2, s0_ = i0 & 3, cs0 = s0_ ^ ((r0 >> 1) & 3);
  const int i1 = t + 256, r1 = i1 >> 2, s1_ = i1 & 3, cs1 = s1_ ^ ((r1 >> 1) & 3);

  // Decode both tiles.
  int bm0, bn0, bm1, bn1;
  tri_decode(blockIdx.x, bm0, bn0);
  tri_decode(blockIdx.x + GRID_P, bm1, bn1);

  // Per-lane fragment LDS offsets (XOR-swizzled 16B slot within each 64B row).
  int aoff[4], boff[4];
  #pragma unroll
  for (int mi = 0; mi < 4; ++mi) {
    const int ar = wr * 64 + mi * 16 + (lane & 15);
    const int sw = (lane >> 4) ^ ((ar >> 1) & 3);
    aoff[mi] = ar * 32 + sw * 8;
  }
  #pragma unroll
  for (int ni = 0; ni < 4; ++ni) {
    const int br = wc * 64 + ni * 16 + (lane & 15);
    const int sw = (lane >> 4) ^ ((br >> 1) & 3);
    boff[ni] = br * 32 + sw * 8;
  }

  // Prologue for tile 0: stage k-tile 0 -> buf0, k-tile 1 -> buf1.
  {
    const int rowA = bm0 * 128, rowB = bn0 * 128;
    const ushort* zA0 = z + (size_t)(rowA + r0) * KDIM + cs0 * 8;
    const ushort* zB0 = z + (size_t)(rowB + r0) * KDIM + cs0 * 8;
    const ushort* zA1 = z + (size_t)(rowA + r1) * KDIM + cs1 * 8;
    const ushort* zB1 = z + (size_t)(rowB + r1) * KDIM + cs1 * 8;
    gload16(zA0,      ASb + (size_t)i0 * 8);
    gload16(zB0,      BSb + (size_t)i0 * 8);
    gload16(zA1,      ASb + (size_t)i1 * 8);
    gload16(zB1,      BSb + (size_t)i1 * 8);
    gload16(zA0 + 32, ASb + 4096 + (size_t)i0 * 8);
    gload16(zB0 + 32, BSb + 4096 + (size_t)i0 * 8);
    gload16(zA1 + 32, ASb + 4096 + (size_t)i1 * 8);
    gload16(zB1 + 32, BSb + 4096 + (size_t)i1 * 8);
  }

  for (int tt = 0; tt < 2; ++tt) {
    const int bm = tt ? bm1 : bm0, bn = tt ? bn1 : bn0;
    const bool offd = (bm != bn);
    const int rowA = bm * 128, rowB = bn * 128;
    const ushort* zA0 = z + (size_t)(rowA + r0) * KDIM + cs0 * 8;
    const ushort* zB0 = z + (size_t)(rowB + r0) * KDIM + cs0 * 8;
    const ushort* zA1 = z + (size_t)(rowA + r1) * KDIM + cs1 * 8;
    const ushort* zB1 = z + (size_t)(rowB + r1) * KDIM + cs1 * 8;

    if (tt) __syncthreads();       // prev tile's fix_loc/cnt readers done
    if (t < 128) { cntA[t] = 0; cntB[t] = 0; }
    if (t == 0) fix_loc_n = 0;

    f32x4 acc[4][4];
    #pragma unroll
    for (int i = 0; i < 4; ++i)
      #pragma unroll
      for (int j = 0; j < 4; ++j) acc[i][j] = (f32x4)0.f;

    int cur = 0;
    // Per K-step: wait MY tile-kt loads -> barrier -> ds_read frags ->
    // lgkmcnt(0)+sched_barrier (rule #18) -> barrier -> restage buf[cur] -> MFMA.
#define KSTEP(VMWAIT, STAGE_KB)                                                   \
  {                                                                               \
    asm volatile("s_waitcnt " VMWAIT ::: "memory");                               \
    __builtin_amdgcn_s_barrier();                                                 \
    __builtin_amdgcn_sched_barrier(0);                                            \
    const ushort* Ac = ASb + cur * 4096;                                          \
    const ushort* Bc = BSb + cur * 4096;                                          \
    bf16x8 af[4], bfv[4];                                                         \
    _Pragma("unroll")                                                             \
    for (int mi = 0; mi < 4; ++mi) af[mi] = *(const bf16x8*)(Ac + aoff[mi]);      \
    _Pragma("unroll")                                                             \
    for (int ni = 0; ni < 4; ++ni) bfv[ni] = *(const bf16x8*)(Bc + boff[ni]);     \
    asm volatile("s_waitcnt lgkmcnt(0)" ::: "memory");                            \
    __builtin_amdgcn_sched_barrier(0);                                            \
    __builtin_amdgcn_s_barrier();                                                 \
    __builtin_amdgcn_sched_barrier(0);                                            \
    if ((STAGE_KB) >= 0) {                                                        \
      const int kb = (STAGE_KB);                                                  \
      ushort* An = ASb + cur * 4096;                                              \
      ushort* Bn = BSb + cur * 4096;                                              \
      gload16(zA0 + kb, An + (size_t)i0 * 8);                                     \
      gload16(zB0 + kb, Bn + (size_t)i0 * 8);                                     \
      gload16(zA1 + kb, An + (size_t)i1 * 8);                                     \
      gload16(zB1 + kb, Bn + (size_t)i1 * 8);                                     \
    }                                                                             \
    _Pragma("unroll")                                                             \
    for (int mi = 0; mi < 4; ++mi)                                                \
      _Pragma("unroll")                                                           \
      for (int ni = 0; ni < 4; ++ni)                                              \
        acc[mi][ni] = __builtin_amdgcn_mfma_f32_16x16x32_bf16(af[mi], bfv[ni],    \
                                                              acc[mi][ni], 0, 0, 0); \
    cur ^= 1;                                                                     \
  }

    for (int kt = 0; kt < 14; ++kt) KSTEP("vmcnt(4)", (kt + 2) * 32);
    KSTEP("vmcnt(4)", -1);
    KSTEP("vmcnt(0)", -1);
#undef KSTEP

    // Direct epilogue: threshold + plain store own tile (L2 merges segments, r14);
    // counts & near-threshold candidates -> LDS.
    // C/D layout (m89-verified): col = lane&15, row = (lane>>4)*4 + reg.
    #pragma unroll
    for (int mi = 0; mi < 4; ++mi) {
      #pragma unroll
      for (int ni = 0; ni < 4; ++ni) {
        const f32x4 v = acc[mi][ni];
        const int lc = wc * 64 + ni * 16 + (lane & 15);
        const int gc = rowB + lc;
        const int lrbase = wr * 64 + mi * 16 + (lane >> 4) * 4;
        #pragma unroll
        for (int r = 0; r < 4; ++r) {
          const float val = v[r];
          const int lr = lrbase + r;
          out[(size_t)(rowA + lr) * NROWS + gc] = (val < THRESH) ? 0.0f : val;
          if (val >= THRESH - MARGIN) {
            atomicAdd(&cntA[lr], 1);
            if (offd) atomicAdd(&cntB[lc], 1);
            if (val < THRESH + MARGIN) {
              const int p = atomicAdd(&fix_loc_n, 1);
              if (p < BLK_FIX_CAP) fix_loc[p] = (uint32_t)(rowA + lr) * NROWS + gc;
            }
          }
        }
      }
    }

    // Mirror epilogue (off-diagonal): paired chunk transpose, all 4 waves active.
    if (offd) {
      #pragma unroll
      for (int p = 0; p < 2; ++p) {
        __syncthreads();   // T2 free
        {
          #pragma unroll
          for (int ni2 = 0; ni2 < 2; ++ni2) {
            const int ni = p * 2 + ni2;                 // this wave's chunk is p+2*wc
            const int tc = ni2 * 16 + (lane & 15);
            #pragma unroll
            for (int mi = 0; mi < 4; ++mi) {
              const int lrb = wr * 64 + mi * 16 + (lane >> 4) * 4;
              #pragma unroll
              for (int r = 0; r < 4; ++r) T2[wc][tc][lrb + r] = acc[mi][ni][r];
            }
          }
        }
        __syncthreads();
        #pragma unroll
        for (int h = 0; h < 2; ++h) {
          const int c = p + 2 * h;
          #pragma unroll
          for (int it = 0; it < 8; ++it) {
            const int j = it * 4 + wv;
            const int i = (t & 63) * 2;
            f32x2 v2 = *(const f32x2*)&T2[h][j][i];
            v2.x = (v2.x < THRESH) ? 0.0f : v2.x;
            v2.y = (v2.y < THRESH) ? 0.0f : v2.y;
            __builtin_nontemporal_store(v2,
                (f32x2*)&out[(size_t)(rowB + c * 32 + j) * NROWS + rowA + i]);
          }
        }
      }
    }
    __syncthreads();   // full drain: stores complete; fix_loc final; T2 dead

    // Cross-tile prefetch: issue tile-1 prologue staging NOW (queue empty, LDS free)
    // so its latency hides under the fixup below.
    if (tt == 0) {
      const int rA1 = bm1 * 128, rB1 = bn1 * 128;
      const ushort* nA0 = z + (size_t)(rA1 + r0) * KDIM + cs0 * 8;
      const ushort* nB0 = z + (size_t)(rB1 + r0) * KDIM + cs0 * 8;
      const ushort* nA1 = z + (size_t)(rA1 + r1) * KDIM + cs1 * 8;
      const ushort* nB1 = z + (size_t)(rB1 + r1) * KDIM + cs1 * 8;
      gload16(nA0,      ASb + (size_t)i0 * 8);
      gload16(nB0,      BSb + (size_t)i0 * 8);
      gload16(nA1,      ASb + (size_t)i1 * 8);
      gload16(nB1,      BSb + (size_t)i1 * 8);
      gload16(nA0 + 32, ASb + 4096 + (size_t)i0 * 8);
      gload16(nB0 + 32, BSb + 4096 + (size_t)i0 * 8);
      gload16(nA1 + 32, ASb + 4096 + (size_t)i1 * 8);
      gload16(nB1 + 32, BSb + 4096 + (size_t)i1 * 8);
    }

    // Fused fixup: exact f64 recompute of near-threshold entries from x, w.
    {
      const int nf = (fix_loc_n < BLK_FIX_CAP) ? fix_loc_n : BLK_FIX_CAP;
      for (int e = wv; e < nf; e += 4) {
        const uint32_t f = fix_loc[e];
        const int r = (int)(f / NROWS), c = (int)(f % NROWS);
        double dot0 = 0, dot1 = 0, nr0 = 0, nr1 = 0, nc0 = 0, nc1 = 0;
        #pragma unroll
        for (int i2 = 0; i2 < DIM / 64; ++i2) {
          const int i = i2 * 64 + lane;
          const double w0 = (double)w[i],              w1 = (double)w[DIM + i];
          const double xr = (double)x[(size_t)r * DIM + i];
          const double xc = (double)x[(size_t)c * DIM + i];
          const double pr0 = xr * w0, pc0 = xc * w0;
          const double pr1 = xr * w1, pc1 = xc * w1;
          dot0 += pr0 * pc0; nr0 += pr0 * pr0; nc0 += pc0 * pc0;
          dot1 += pr1 * pc1; nr1 += pr1 * pr1; nc1 += pc1 * pc1;
        }
        #pragma unroll
        for (int off = 32; off > 0; off >>= 1) {
          dot0 += __shfl_down(dot0, off); nr0 += __shfl_down(nr0, off); nc0 += __shfl_down(nc0, off);
          dot1 += __shfl_down(dot1, off); nr1 += __shfl_down(nr1, off); nc1 += __shfl_down(nc1, off);
        }
        if (lane == 0) {
          const double s0 = dot0 / (fmax(sqrt(nr0), 1e-8) * fmax(sqrt(nc0), 1e-8));
          const double s1 = dot1 / (fmax(sqrt(nr1), 1e-8) * fmax(sqrt(nc1), 1e-8));
          const double sim = 0.5 * (s0 + s1);
          const float res = (sim < (double)THRESH) ? 0.0f : (float)sim;
          out[(size_t)r * NROWS + c] = res;
          out[(size_t)c * NROWS + r] = res;   // twin (self for diagonal entries)
        }
      }
    }

    // Flush per-row count atomics (sparse).
    if (t < 128) {
      if (cntA[t] > 0) atomicAdd(&cnt[rowA + t], cntA[t]);
      if (offd && cntB[t] > 0) atomicAdd(&cnt[rowB + t], cntB[t]);
    }
  }
}

// ---------------- Pass 3: stable top-K fix for (rare) rows with more than K kept
// entries. 8 rows per block (block-uniform early-continue) to cut dispatch count.
__global__ __launch_bounds__(256) void topk_fix(float* __restrict__ out,
                                                const int* __restrict__ cnt,
                                                const int* __restrict__ Kp) {
  const int K = Kp[0];
  __shared__ float vals[TOPK_CAP];
  __shared__ int   idxs[TOPK_CAP];
  __shared__ int   num;
  for (int rr = 0; rr < 8; ++rr) {
    const int row = blockIdx.x * 8 + rr;
    if (cnt[row] <= K) continue;   // block-uniform; common case

    if (threadIdx.x == 0) num = 0;
    __syncthreads();
    for (int j = threadIdx.x; j < NROWS; j += 256) {
      const float v = out[(size_t)row * NROWS + j];
      if (v != 0.0f) {
        const int p = atomicAdd(&num, 1);
        if (p < TOPK_CAP) { vals[p] = v; idxs[p] = j; }
      }
    }
    __syncthreads();
    const int c = (num < TOPK_CAP) ? num : TOPK_CAP;
    // Stable rank = #{q : v_q > v_p or (v_q == v_p and idx_q < idx_p)}; keep rank < K.
    for (int p = threadIdx.x; p < c; p += 256) {
      const float v = vals[p];
      const int  id = idxs[p];
      int rank = 0;
      for (int q = 0; q < c; ++q) {
        const float u = vals[q];
        rank += (u > v) || (u == v && idxs[q] < id);
      }
      if (rank >= K) out[(size_t)row * NROWS + id] = 0.0f;
    }
    __syncthreads();   // vals/idxs/num free before next triggered row
  }
}

extern "C" void kernel_launch(void* const* d_in, const int* in_sizes, int n_in,
                              void* d_out, int out_size, void* d_ws, size_t ws_size,
                              hipStream_t stream) {
  const float* x  = (const float*)d_in[0];
  const float* w  = (const float*)d_in[1];
  const int*   Kp = (const int*)d_in[2];
  float* out = (float*)d_out;

  char* ws = (char*)d_ws;
  ushort* z   = (ushort*)ws;                            // 8 MB
  int*    cnt = (int*)(ws + (size_t)NROWS * KDIM * 2);  // 32 KB

  prep_k<<<NROWS / 4, 256, 0, stream>>>(x, w, z, cnt);      // wave-per-row
  sim_gemm<<<GRID_P, 256, 0, stream>>>(z, x, w, out, cnt);  // persistent, 2 tiles/block
  topk_fix<<<NROWS / 8, 256, 0, stream>>>(out, cnt, Kp);    // 8 rows/block
}

// Round 18
// 118.131 us; speedup vs baseline: 1.6281x; 1.6281x over previous
//
#include <hip/hip_runtime.h>
#include <hip/hip_bf16.h>
#include <stdint.h>

#define NROWS 8192
#define DIM   256
#define KDIM  512          // H*D concatenated
#define THRESH 0.2f
#define MARGIN 0.005f      // hard bound on |bf16-gemm val - f64 true sim|
#define BLK_FIX_CAP 512    // ~23 expected candidates per 128x128 block
#define TOPK_CAP 4096

typedef __bf16 bf16x8 __attribute__((ext_vector_type(8)));
typedef float  f32x4  __attribute__((ext_vector_type(4)));
typedef float  f32x2  __attribute__((ext_vector_type(2)));

__device__ __forceinline__ void gload16(const void* g, void* l) {
  __builtin_amdgcn_global_load_lds(
      (const __attribute__((address_space(1))) uint32_t*)g,
      (__attribute__((address_space(3))) uint32_t*)l,
      16, 0, 0);
}

// ---------------- Pass 1: z[n][512] = concat_h( (x*w_h)/max(||x*w_h||,eps) ) / sqrt(2), bf16.
// One wave per row (4 rows/block): float4 loads, butterfly reduce, no LDS/sync.
// Also zeroes cnt (folded memset).
__global__ __launch_bounds__(256) void prep_k(const float* __restrict__ x,
                                              const float* __restrict__ w,
                                              ushort* __restrict__ z,
                                              int* __restrict__ cnt) {
  const int wv = threadIdx.x >> 6, lane = threadIdx.x & 63;
  const int n = blockIdx.x * 4 + wv;
  if (lane == 0) cnt[n] = 0;
  const int d4 = lane * 4;
  const f32x4 xv = *(const f32x4*)&x[(size_t)n * DIM + d4];
  const f32x4 w0 = *(const f32x4*)&w[d4];
  const f32x4 w1 = *(const f32x4*)&w[DIM + d4];
  f32x4 p0, p1;
  float s0 = 0.f, s1 = 0.f;
  #pragma unroll
  for (int j = 0; j < 4; ++j) {
    p0[j] = xv[j] * w0[j];  s0 += p0[j] * p0[j];
    p1[j] = xv[j] * w1[j];  s1 += p1[j] * p1[j];
  }
  #pragma unroll
  for (int off = 32; off > 0; off >>= 1) {
    s0 += __shfl_xor(s0, off);
    s1 += __shfl_xor(s1, off);
  }
  const float inv0 = 0.70710678118654752f / fmaxf(sqrtf(s0), 1e-8f);
  const float inv1 = 0.70710678118654752f / fmaxf(sqrtf(s1), 1e-8f);
  ushort4 o0, o1;
  {
    __hip_bfloat16 b;
    b = __float2bfloat16(p0[0] * inv0); o0.x = *(ushort*)&b;
    b = __float2bfloat16(p0[1] * inv0); o0.y = *(ushort*)&b;
    b = __float2bfloat16(p0[2] * inv0); o0.z = *(ushort*)&b;
    b = __float2bfloat16(p0[3] * inv0); o0.w = *(ushort*)&b;
    b = __float2bfloat16(p1[0] * inv1); o1.x = *(ushort*)&b;
    b = __float2bfloat16(p1[1] * inv1); o1.y = *(ushort*)&b;
    b = __float2bfloat16(p1[2] * inv1); o1.z = *(ushort*)&b;
    b = __float2bfloat16(p1[3] * inv1); o1.w = *(ushort*)&b;
  }
  *(ushort4*)&z[(size_t)n * KDIM + d4]       = o0;
  *(ushort4*)&z[(size_t)n * KDIM + DIM + d4] = o1;
}

// ---------------- Pass 2: sim = Z Z^T, upper-triangle blocks (1D triangular grid);
// counted-vmcnt 2-deep pipeline; dense epilogue (direct stores from acc + paired-chunk
// LDS-transposed mirror, nt on the contiguous mirror only); fused f64 fixup.
// __launch_bounds__(256,4): cap VGPR at 128 -> 4 blocks/CU resident (r16: +4us).
// NOTE (r17): do NOT wrap this body in a persistent multi-tile loop — regalloc
// spills acc to scratch (VGPR 64, +190MB scratch traffic, 200us).
__global__ __launch_bounds__(256, 4) void sim_gemm(const ushort* __restrict__ z,
                                               const float* __restrict__ x,
                                               const float* __restrict__ w,
                                               float* __restrict__ out,
                                               int* __restrict__ cnt) {
  // Triangular decode: block u -> (bm, bn), bm<=bn, T(bm)=bm*(129-bm)/2.
  const int u = blockIdx.x;
  int bm = (int)((129.0 - sqrt(129.0 * 129.0 - 8.0 * (double)u)) * 0.5);
  if (bm > 63) bm = 63;
  while (bm * (129 - bm) / 2 > u) --bm;
  while ((bm + 1) * (129 - (bm + 1)) / 2 <= u) ++bm;
  const int bn = bm + (u - bm * (129 - bm) / 2);
  const bool offd = (bm != bn);

  // Stage buffers (2x dbuf x (As+Bs) = 32 KB) aliased with the post-loop paired
  // transpose buffer T2[2][32][130] (33.3 KB): T2 only used after the loop's
  // final barrier. Union size = max(32768, 33280) = 33280.
  __shared__ __align__(16) char smem[33280];
  ushort* ASb = (ushort*)smem;               // ASb + b*4096 : A stage buffer b
  ushort* BSb = (ushort*)(smem + 16384);     // BSb + b*4096 : B stage buffer b
  auto T2 = (float (*)[32][130])smem;        // alias, post-loop only
  __shared__ int cntA[128], cntB[128];
  __shared__ uint32_t fix_loc[BLK_FIX_CAP];
  __shared__ int fix_loc_n;

  const int t = threadIdx.x;
  const int rowA = bm * 128, rowB = bn * 128;
  const int wv = t >> 6, lane = t & 63;
  const int wr = wv >> 1, wc = wv & 1;

  f32x4 acc[4][4];
  #pragma unroll
  for (int i = 0; i < 4; ++i)
    #pragma unroll
    for (int j = 0; j < 4; ++j) acc[i][j] = (f32x4)0.f;

  // Per-lane fragment LDS offsets (XOR-swizzled 16B slot within each 64B row).
  int aoff[4], boff[4];
  #pragma unroll
  for (int mi = 0; mi < 4; ++mi) {
    const int ar = wr * 64 + mi * 16 + (lane & 15);
    const int sw = (lane >> 4) ^ ((ar >> 1) & 3);
    aoff[mi] = ar * 32 + sw * 8;
  }
  #pragma unroll
  for (int ni = 0; ni < 4; ++ni) {
    const int br = wc * 64 + ni * 16 + (lane & 15);
    const int sw = (lane >> 4) ^ ((br >> 1) & 3);
    boff[ni] = br * 32 + sw * 8;
  }

  if (t < 128) { cntA[t] = 0; cntB[t] = 0; }
  if (t == 0) fix_loc_n = 0;

  // Per-thread staging slot (constant across iters).
  const int i0 = t, r0 = i0 >> 2, s0_ = i0 & 3, cs0 = s0_ ^ ((r0 >> 1) & 3);
  const int i1 = t + 256, r1 = i1 >> 2, s1_ = i1 & 3, cs1 = s1_ ^ ((r1 >> 1) & 3);
  const ushort* zA0 = z + (size_t)(rowA + r0) * KDIM + cs0 * 8;
  const ushort* zB0 = z + (size_t)(rowB + r0) * KDIM + cs0 * 8;
  const ushort* zA1 = z + (size_t)(rowA + r1) * KDIM + cs1 * 8;
  const ushort* zB1 = z + (size_t)(rowB + r1) * KDIM + cs1 * 8;

  // Prologue: stage tile 0 -> buf0, tile 1 -> buf1 (8 loads in flight, no drain).
  gload16(zA0,      ASb + (size_t)i0 * 8);
  gload16(zB0,      BSb + (size_t)i0 * 8);
  gload16(zA1,      ASb + (size_t)i1 * 8);
  gload16(zB1,      BSb + (size_t)i1 * 8);
  gload16(zA0 + 32, ASb + 4096 + (size_t)i0 * 8);
  gload16(zB0 + 32, BSb + 4096 + (size_t)i0 * 8);
  gload16(zA1 + 32, ASb + 4096 + (size_t)i1 * 8);
  gload16(zB1 + 32, BSb + 4096 + (size_t)i1 * 8);

  int cur = 0;
  // Per K-step: wait MY tile-kt loads (vmcnt leaves kt+1's 4 in flight) -> barrier
  // (ALL waves' tile-kt loads landed) -> ds_read frags -> lgkmcnt(0)+sched_barrier
  // (rule #18) -> barrier (ALL reads consumed) -> restage buf[cur] with tile kt+2 -> MFMA.
#define KSTEP(VMWAIT, STAGE_KB)                                                   \
  {                                                                               \
    asm volatile("s_waitcnt " VMWAIT ::: "memory");                               \
    __builtin_amdgcn_s_barrier();                                                 \
    __builtin_amdgcn_sched_barrier(0);                                            \
    const ushort* Ac = ASb + cur * 4096;                                          \
    const ushort* Bc = BSb + cur * 4096;                                          \
    bf16x8 af[4], bfv[4];                                                         \
    _Pragma("unroll")                                                             \
    for (int mi = 0; mi < 4; ++mi) af[mi] = *(const bf16x8*)(Ac + aoff[mi]);      \
    _Pragma("unroll")                                                             \
    for (int ni = 0; ni < 4; ++ni) bfv[ni] = *(const bf16x8*)(Bc + boff[ni]);     \
    asm volatile("s_waitcnt lgkmcnt(0)" ::: "memory");                            \
    __builtin_amdgcn_sched_barrier(0);                                            \
    __builtin_amdgcn_s_barrier();                                                 \
    __builtin_amdgcn_sched_barrier(0);                                            \
    if ((STAGE_KB) >= 0) {                                                        \
      const int kb = (STAGE_KB);                                                  \
      ushort* An = ASb + cur * 4096;                                              \
      ushort* Bn = BSb + cur * 4096;                                              \
      gload16(zA0 + kb, An + (size_t)i0 * 8);                                     \
      gload16(zB0 + kb, Bn + (size_t)i0 * 8);                                     \
      gload16(zA1 + kb, An + (size_t)i1 * 8);                                     \
      gload16(zB1 + kb, Bn + (size_t)i1 * 8);                                     \
    }                                                                             \
    _Pragma("unroll")                                                             \
    for (int mi = 0; mi < 4; ++mi)                                                \
      _Pragma("unroll")                                                           \
      for (int ni = 0; ni < 4; ++ni)                                              \
        acc[mi][ni] = __builtin_amdgcn_mfma_f32_16x16x32_bf16(af[mi], bfv[ni],    \
                                                              acc[mi][ni], 0, 0, 0); \
    cur ^= 1;                                                                     \
  }

  for (int kt = 0; kt < 14; ++kt) KSTEP("vmcnt(4)", (kt + 2) * 32);
  KSTEP("vmcnt(4)", -1);   // kt=14: only tile 15 left in flight
  KSTEP("vmcnt(0)", -1);   // kt=15: drain remaining
#undef KSTEP

  // Direct epilogue: threshold + plain store own tile (L2 merges the 4x64B
  // segments per instr — verified neutral vs LDS-transposed full lines, r14);
  // counts & near-threshold candidates -> LDS.
  // C/D layout (m89-verified): col = lane&15, row = (lane>>4)*4 + reg.
  #pragma unroll
  for (int mi = 0; mi < 4; ++mi) {
    #pragma unroll
    for (int ni = 0; ni < 4; ++ni) {
      const f32x4 v = acc[mi][ni];
      const int lc = wc * 64 + ni * 16 + (lane & 15);   // local col
      const int gc = rowB + lc;
      const int lrbase = wr * 64 + mi * 16 + (lane >> 4) * 4;  // local row
      #pragma unroll
      for (int r = 0; r < 4; ++r) {
        const float val = v[r];
        const int lr = lrbase + r;
        out[(size_t)(rowA + lr) * NROWS + gc] = (val < THRESH) ? 0.0f : val;
        if (val >= THRESH - MARGIN) {
          atomicAdd(&cntA[lr], 1);               // LDS atomic (upper bound, A-row stripe)
          if (offd) atomicAdd(&cntB[lc], 1);     // symmetric contribution to B-rows
          if (val < THRESH + MARGIN) {
            const int p = atomicAdd(&fix_loc_n, 1);
            if (p < BLK_FIX_CAP) fix_loc[p] = (uint32_t)(rowA + lr) * NROWS + gc;
          }
        }
      }
    }
  }

  // Mirror epilogue (off-diagonal blocks): paired chunk transpose — both wave-column
  // halves fill their chunk concurrently (chunks c=p and c=p+2), all 4 waves active.
  if (offd) {
    #pragma unroll
    for (int p = 0; p < 2; ++p) {
      __syncthreads();   // T2 free (stage reads / prev pair readers done)
      {
        #pragma unroll
        for (int ni2 = 0; ni2 < 2; ++ni2) {
          const int ni = p * 2 + ni2;                   // this wave's chunk is p+2*wc
          const int tc = ni2 * 16 + (lane & 15);        // col within chunk 0..31
          #pragma unroll
          for (int mi = 0; mi < 4; ++mi) {
            const int lrb = wr * 64 + mi * 16 + (lane >> 4) * 4;
            #pragma unroll
            for (int r = 0; r < 4; ++r) T2[wc][tc][lrb + r] = acc[mi][ni][r];
          }
        }
      }
      __syncthreads();
      // 2 chunks x 8 iters: 4 mirror rows x 64 lanes x f32x2 (512B contiguous per wave)
      #pragma unroll
      for (int h = 0; h < 2; ++h) {
        const int c = p + 2 * h;
        #pragma unroll
        for (int it = 0; it < 8; ++it) {
          const int j = it * 4 + wv;                    // chunk-local mirror row 0..31
          const int i = (t & 63) * 2;                   // col in 0..127
          f32x2 v2 = *(const f32x2*)&T2[h][j][i];
          v2.x = (v2.x < THRESH) ? 0.0f : v2.x;
          v2.y = (v2.y < THRESH) ? 0.0f : v2.y;
          __builtin_nontemporal_store(v2,
              (f32x2*)&out[(size_t)(rowB + c * 32 + j) * NROWS + rowA + i]);
        }
      }
    }
  }
  __syncthreads();   // drains vmcnt: all thresholded stores complete; fix_loc final

  // Fused fixup: exact f64 recompute of this block's near-threshold entries from x, w.
  // Writes both (r,c) and (c,r) — twin has the identical bf16-gemm value.
  {
    const int nf = (fix_loc_n < BLK_FIX_CAP) ? fix_loc_n : BLK_FIX_CAP;
    for (int e = wv; e < nf; e += 4) {
      const uint32_t f = fix_loc[e];
      const int r = (int)(f / NROWS), c = (int)(f % NROWS);
      double dot0 = 0, dot1 = 0, nr0 = 0, nr1 = 0, nc0 = 0, nc1 = 0;
      #pragma unroll
      for (int i2 = 0; i2 < DIM / 64; ++i2) {
        const int i = i2 * 64 + lane;
        const double w0 = (double)w[i],              w1 = (double)w[DIM + i];
        const double xr = (double)x[(size_t)r * DIM + i];
        const double xc = (double)x[(size_t)c * DIM + i];
        const double pr0 = xr * w0, pc0 = xc * w0;
        const double pr1 = xr * w1, pc1 = xc * w1;
        dot0 += pr0 * pc0; nr0 += pr0 * pr0; nc0 += pc0 * pc0;
        dot1 += pr1 * pc1; nr1 += pr1 * pr1; nc1 += pc1 * pc1;
      }
      #pragma unroll
      for (int off = 32; off > 0; off >>= 1) {
        dot0 += __shfl_down(dot0, off); nr0 += __shfl_down(nr0, off); nc0 += __shfl_down(nc0, off);
        dot1 += __shfl_down(dot1, off); nr1 += __shfl_down(nr1, off); nc1 += __shfl_down(nc1, off);
      }
      if (lane == 0) {
        const double s0 = dot0 / (fmax(sqrt(nr0), 1e-8) * fmax(sqrt(nc0), 1e-8));
        const double s1 = dot1 / (fmax(sqrt(nr1), 1e-8) * fmax(sqrt(nc1), 1e-8));
        const double sim = 0.5 * (s0 + s1);
        const float res = (sim < (double)THRESH) ? 0.0f : (float)sim;
        out[(size_t)r * NROWS + c] = res;
        out[(size_t)c * NROWS + r] = res;   // twin (self for diagonal entries)
      }
    }
  }

  // Flush per-row count atomics (sparse).
  if (t < 128) {
    if (cntA[t] > 0) atomicAdd(&cnt[rowA + t], cntA[t]);
    if (offd && cntB[t] > 0) atomicAdd(&cnt[rowB + t], cntB[t]);
  }
}

// ---------------- Pass 3: stable top-K fix for (rare) rows with more than K kept
// entries. 8 rows per block (block-uniform early-continue) to cut dispatch count.
__global__ __launch_bounds__(256) void topk_fix(float* __restrict__ out,
                                                const int* __restrict__ cnt,
                                                const int* __restrict__ Kp) {
  const int K = Kp[0];
  __shared__ float vals[TOPK_CAP];
  __shared__ int   idxs[TOPK_CAP];
  __shared__ int   num;
  for (int rr = 0; rr < 8; ++rr) {
    const int row = blockIdx.x * 8 + rr;
    if (cnt[row] <= K) continue;   // block-uniform; common case

    if (threadIdx.x == 0) num = 0;
    __syncthreads();
    for (int j = threadIdx.x; j < NROWS; j += 256) {
      const float v = out[(size_t)row * NROWS + j];
      if (v != 0.0f) {
        const int p = atomicAdd(&num, 1);
        if (p < TOPK_CAP) { vals[p] = v; idxs[p] = j; }
      }
    }
    __syncthreads();
    const int c = (num < TOPK_CAP) ? num : TOPK_CAP;
    // Stable rank = #{q : v_q > v_p or (v_q == v_p and idx_q < idx_p)}; keep rank < K.
    for (int p = threadIdx.x; p < c; p += 256) {
      const float v = vals[p];
      const int  id = idxs[p];
      int rank = 0;
      for (int q = 0; q < c; ++q) {
        const float u = vals[q];
        rank += (u > v) || (u == v && idxs[q] < id);
      }
      if (rank >= K) out[(size_t)row * NROWS + id] = 0.0f;
    }
    __syncthreads();   // vals/idxs/num free before next triggered row
  }
}

extern "C" void kernel_launch(void* const* d_in, const int* in_sizes, int n_in,
                              void* d_out, int out_size, void* d_ws, size_t ws_size,
                              hipStream_t stream) {
  const float* x  = (const float*)d_in[0];
  const float* w  = (const float*)d_in[1];
  const int*   Kp = (const int*)d_in[2];
  float* out = (float*)d_out;

  char* ws = (char*)d_ws;
  ushort* z   = (ushort*)ws;                            // 8 MB
  int*    cnt = (int*)(ws + (size_t)NROWS * KDIM * 2);  // 32 KB

  prep_k<<<NROWS / 4, 256, 0, stream>>>(x, w, z, cnt);      // wave-per-row
  sim_gemm<<<2080, 256, 0, stream>>>(z, x, w, out, cnt);    // 64*65/2 upper-tri blocks
  topk_fix<<<NROWS / 8, 256, 0, stream>>>(out, cnt, Kp);    // 8 rows/block
}

// Round 19
// 113.865 us; speedup vs baseline: 1.6891x; 1.0375x over previous
//
#include <hip/hip_runtime.h>
#include <hip/hip_bf16.h>
#include <stdint.h>

#define NROWS 8192
#define DIM   256
#define KDIM  512          // H*D concatenated
#define THRESH 0.2f
#define MARGIN 0.005f      // hard bound on |bf16-gemm val - f64 true sim|
#define BLK_FIX_CAP 512    // ~23 expected candidates per 128x128 block
#define TOPK_CAP 4096

typedef __bf16 bf16x8 __attribute__((ext_vector_type(8)));
typedef float  f32x4  __attribute__((ext_vector_type(4)));
typedef float  f32x2  __attribute__((ext_vector_type(2)));

__device__ __forceinline__ void gload16(const void* g, void* l) {
  __builtin_amdgcn_global_load_lds(
      (const __attribute__((address_space(1))) uint32_t*)g,
      (__attribute__((address_space(3))) uint32_t*)l,
      16, 0, 0);
}

// ---------------- Pass 1: z[n][512] = concat_h( (x*w_h)/max(||x*w_h||,eps) ) / sqrt(2), bf16.
// One wave per row (4 rows/block): float4 loads, butterfly reduce, no LDS/sync.
// Also zeroes cnt (folded memset).
__global__ __launch_bounds__(256) void prep_k(const float* __restrict__ x,
                                              const float* __restrict__ w,
                                              ushort* __restrict__ z,
                                              int* __restrict__ cnt) {
  const int wv = threadIdx.x >> 6, lane = threadIdx.x & 63;
  const int n = blockIdx.x * 4 + wv;
  if (lane == 0) cnt[n] = 0;
  const int d4 = lane * 4;
  const f32x4 xv = *(const f32x4*)&x[(size_t)n * DIM + d4];
  const f32x4 w0 = *(const f32x4*)&w[d4];
  const f32x4 w1 = *(const f32x4*)&w[DIM + d4];
  f32x4 p0, p1;
  float s0 = 0.f, s1 = 0.f;
  #pragma unroll
  for (int j = 0; j < 4; ++j) {
    p0[j] = xv[j] * w0[j];  s0 += p0[j] * p0[j];
    p1[j] = xv[j] * w1[j];  s1 += p1[j] * p1[j];
  }
  #pragma unroll
  for (int off = 32; off > 0; off >>= 1) {
    s0 += __shfl_xor(s0, off);
    s1 += __shfl_xor(s1, off);
  }
  const float inv0 = 0.70710678118654752f / fmaxf(sqrtf(s0), 1e-8f);
  const float inv1 = 0.70710678118654752f / fmaxf(sqrtf(s1), 1e-8f);
  ushort4 o0, o1;
  {
    __hip_bfloat16 b;
    b = __float2bfloat16(p0[0] * inv0); o0.x = *(ushort*)&b;
    b = __float2bfloat16(p0[1] * inv0); o0.y = *(ushort*)&b;
    b = __float2bfloat16(p0[2] * inv0); o0.z = *(ushort*)&b;
    b = __float2bfloat16(p0[3] * inv0); o0.w = *(ushort*)&b;
    b = __float2bfloat16(p1[0] * inv1); o1.x = *(ushort*)&b;
    b = __float2bfloat16(p1[1] * inv1); o1.y = *(ushort*)&b;
    b = __float2bfloat16(p1[2] * inv1); o1.z = *(ushort*)&b;
    b = __float2bfloat16(p1[3] * inv1); o1.w = *(ushort*)&b;
  }
  *(ushort4*)&z[(size_t)n * KDIM + d4]       = o0;
  *(ushort4*)&z[(size_t)n * KDIM + DIM + d4] = o1;
}

// ---------------- Pass 2: sim = Z Z^T, upper-triangle blocks (1D triangular grid);
// counted-vmcnt 2-deep pipeline; dense epilogue; fused f64 fixup.
// __launch_bounds__(256,4): 4 blocks/CU resident (r16: +4us).
// r17 NOTE: no persistent multi-tile loop (regalloc spills acc).
// r19: dropped sched_barrier after barrier-1 (scheduler freedom); setprio(1)
// around MFMA pack (blocks at different phases = T5 prereq); mirror nt removed (A/B).
__global__ __launch_bounds__(256, 4) void sim_gemm(const ushort* __restrict__ z,
                                               const float* __restrict__ x,
                                               const float* __restrict__ w,
                                               float* __restrict__ out,
                                               int* __restrict__ cnt) {
  // Triangular decode: block u -> (bm, bn), bm<=bn, T(bm)=bm*(129-bm)/2.
  const int u = blockIdx.x;
  int bm = (int)((129.0 - sqrt(129.0 * 129.0 - 8.0 * (double)u)) * 0.5);
  if (bm > 63) bm = 63;
  while (bm * (129 - bm) / 2 > u) --bm;
  while ((bm + 1) * (129 - (bm + 1)) / 2 <= u) ++bm;
  const int bn = bm + (u - bm * (129 - bm) / 2);
  const bool offd = (bm != bn);

  // Stage buffers (2x dbuf x (As+Bs) = 32 KB) aliased with the post-loop paired
  // transpose buffer T2[2][32][130] (33.3 KB): T2 only used after the loop's
  // final barrier. Union size = max(32768, 33280) = 33280.
  __shared__ __align__(16) char smem[33280];
  ushort* ASb = (ushort*)smem;               // ASb + b*4096 : A stage buffer b
  ushort* BSb = (ushort*)(smem + 16384);     // BSb + b*4096 : B stage buffer b
  auto T2 = (float (*)[32][130])smem;        // alias, post-loop only
  __shared__ int cntA[128], cntB[128];
  __shared__ uint32_t fix_loc[BLK_FIX_CAP];
  __shared__ int fix_loc_n;

  const int t = threadIdx.x;
  const int rowA = bm * 128, rowB = bn * 128;
  const int wv = t >> 6, lane = t & 63;
  const int wr = wv >> 1, wc = wv & 1;

  f32x4 acc[4][4];
  #pragma unroll
  for (int i = 0; i < 4; ++i)
    #pragma unroll
    for (int j = 0; j < 4; ++j) acc[i][j] = (f32x4)0.f;

  // Per-lane fragment LDS offsets (XOR-swizzled 16B slot within each 64B row).
  int aoff[4], boff[4];
  #pragma unroll
  for (int mi = 0; mi < 4; ++mi) {
    const int ar = wr * 64 + mi * 16 + (lane & 15);
    const int sw = (lane >> 4) ^ ((ar >> 1) & 3);
    aoff[mi] = ar * 32 + sw * 8;
  }
  #pragma unroll
  for (int ni = 0; ni < 4; ++ni) {
    const int br = wc * 64 + ni * 16 + (lane & 15);
    const int sw = (lane >> 4) ^ ((br >> 1) & 3);
    boff[ni] = br * 32 + sw * 8;
  }

  if (t < 128) { cntA[t] = 0; cntB[t] = 0; }
  if (t == 0) fix_loc_n = 0;

  // Per-thread staging slot (constant across iters).
  const int i0 = t, r0 = i0 >> 2, s0_ = i0 & 3, cs0 = s0_ ^ ((r0 >> 1) & 3);
  const int i1 = t + 256, r1 = i1 >> 2, s1_ = i1 & 3, cs1 = s1_ ^ ((r1 >> 1) & 3);
  const ushort* zA0 = z + (size_t)(rowA + r0) * KDIM + cs0 * 8;
  const ushort* zB0 = z + (size_t)(rowB + r0) * KDIM + cs0 * 8;
  const ushort* zA1 = z + (size_t)(rowA + r1) * KDIM + cs1 * 8;
  const ushort* zB1 = z + (size_t)(rowB + r1) * KDIM + cs1 * 8;

  // Prologue: stage tile 0 -> buf0, tile 1 -> buf1 (8 loads in flight, no drain).
  gload16(zA0,      ASb + (size_t)i0 * 8);
  gload16(zB0,      BSb + (size_t)i0 * 8);
  gload16(zA1,      ASb + (size_t)i1 * 8);
  gload16(zB1,      BSb + (size_t)i1 * 8);
  gload16(zA0 + 32, ASb + 4096 + (size_t)i0 * 8);
  gload16(zB0 + 32, BSb + 4096 + (size_t)i0 * 8);
  gload16(zA1 + 32, ASb + 4096 + (size_t)i1 * 8);
  gload16(zB1 + 32, BSb + 4096 + (size_t)i1 * 8);

  int cur = 0;
  // Per K-step: wait MY tile-kt loads (vmcnt leaves kt+1's 4 in flight) -> barrier
  // (ALL waves' tile-kt loads landed) -> ds_read frags -> lgkmcnt(0)+sched_barrier
  // (rule #18) -> barrier (ALL reads consumed) -> restage buf[cur] with tile kt+2
  // -> setprio-wrapped MFMA.
#define KSTEP(VMWAIT, STAGE_KB)                                                   \
  {                                                                               \
    asm volatile("s_waitcnt " VMWAIT ::: "memory");                               \
    __builtin_amdgcn_s_barrier();                                                 \
    const ushort* Ac = ASb + cur * 4096;                                          \
    const ushort* Bc = BSb + cur * 4096;                                          \
    bf16x8 af[4], bfv[4];                                                         \
    _Pragma("unroll")                                                             \
    for (int mi = 0; mi < 4; ++mi) af[mi] = *(const bf16x8*)(Ac + aoff[mi]);      \
    _Pragma("unroll")                                                             \
    for (int ni = 0; ni < 4; ++ni) bfv[ni] = *(const bf16x8*)(Bc + boff[ni]);     \
    asm volatile("s_waitcnt lgkmcnt(0)" ::: "memory");                            \
    __builtin_amdgcn_sched_barrier(0);                                            \
    __builtin_amdgcn_s_barrier();                                                 \
    __builtin_amdgcn_sched_barrier(0);                                            \
    if ((STAGE_KB) >= 0) {                                                        \
      const int kb = (STAGE_KB);                                                  \
      ushort* An = ASb + cur * 4096;                                              \
      ushort* Bn = BSb + cur * 4096;                                              \
      gload16(zA0 + kb, An + (size_t)i0 * 8);                                     \
      gload16(zB0 + kb, Bn + (size_t)i0 * 8);                                     \
      gload16(zA1 + kb, An + (size_t)i1 * 8);                                     \
      gload16(zB1 + kb, Bn + (size_t)i1 * 8);                                     \
    }                                                                             \
    __builtin_amdgcn_s_setprio(1);                                                \
    _Pragma("unroll")                                                             \
    for (int mi = 0; mi < 4; ++mi)                                                \
      _Pragma("unroll")                                                           \
      for (int ni = 0; ni < 4; ++ni)                                              \
        acc[mi][ni] = __builtin_amdgcn_mfma_f32_16x16x32_bf16(af[mi], bfv[ni],    \
                                                              acc[mi][ni], 0, 0, 0); \
    __builtin_amdgcn_s_setprio(0);                                                \
    cur ^= 1;                                                                     \
  }

  for (int kt = 0; kt < 14; ++kt) KSTEP("vmcnt(4)", (kt + 2) * 32);
  KSTEP("vmcnt(4)", -1);   // kt=14: only tile 15 left in flight
  KSTEP("vmcnt(0)", -1);   // kt=15: drain remaining
#undef KSTEP

  // Direct epilogue: threshold + plain store own tile (L2 merges the 4x64B
  // segments per instr — verified neutral vs LDS-transposed full lines, r14);
  // counts & near-threshold candidates -> LDS.
  // C/D layout (m89-verified): col = lane&15, row = (lane>>4)*4 + reg.
  #pragma unroll
  for (int mi = 0; mi < 4; ++mi) {
    #pragma unroll
    for (int ni = 0; ni < 4; ++ni) {
      const f32x4 v = acc[mi][ni];
      const int lc = wc * 64 + ni * 16 + (lane & 15);   // local col
      const int gc = rowB + lc;
      const int lrbase = wr * 64 + mi * 16 + (lane >> 4) * 4;  // local row
      #pragma unroll
      for (int r = 0; r < 4; ++r) {
        const float val = v[r];
        const int lr = lrbase + r;
        out[(size_t)(rowA + lr) * NROWS + gc] = (val < THRESH) ? 0.0f : val;
        if (val >= THRESH - MARGIN) {
          atomicAdd(&cntA[lr], 1);               // LDS atomic (upper bound, A-row stripe)
          if (offd) atomicAdd(&cntB[lc], 1);     // symmetric contribution to B-rows
          if (val < THRESH + MARGIN) {
            const int p = atomicAdd(&fix_loc_n, 1);
            if (p < BLK_FIX_CAP) fix_loc[p] = (uint32_t)(rowA + lr) * NROWS + gc;
          }
        }
      }
    }
  }

  // Mirror epilogue (off-diagonal blocks): paired chunk transpose — both wave-column
  // halves fill their chunk concurrently (chunks c=p and c=p+2), all 4 waves active.
  if (offd) {
    #pragma unroll
    for (int p = 0; p < 2; ++p) {
      __syncthreads();   // T2 free (stage reads / prev pair readers done)
      {
        #pragma unroll
        for (int ni2 = 0; ni2 < 2; ++ni2) {
          const int ni = p * 2 + ni2;                   // this wave's chunk is p+2*wc
          const int tc = ni2 * 16 + (lane & 15);        // col within chunk 0..31
          #pragma unroll
          for (int mi = 0; mi < 4; ++mi) {
            const int lrb = wr * 64 + mi * 16 + (lane >> 4) * 4;
            #pragma unroll
            for (int r = 0; r < 4; ++r) T2[wc][tc][lrb + r] = acc[mi][ni][r];
          }
        }
      }
      __syncthreads();
      // 2 chunks x 8 iters: 4 mirror rows x 64 lanes x f32x2 (512B contiguous per wave)
      #pragma unroll
      for (int h = 0; h < 2; ++h) {
        const int c = p + 2 * h;
        #pragma unroll
        for (int it = 0; it < 8; ++it) {
          const int j = it * 4 + wv;                    // chunk-local mirror row 0..31
          const int i = (t & 63) * 2;                   // col in 0..127
          f32x2 v2 = *(const f32x2*)&T2[h][j][i];
          v2.x = (v2.x < THRESH) ? 0.0f : v2.x;
          v2.y = (v2.y < THRESH) ? 0.0f : v2.y;
          *(f32x2*)&out[(size_t)(rowB + c * 32 + j) * NROWS + rowA + i] = v2;
        }
      }
    }
  }
  __syncthreads();   // drains vmcnt: all thresholded stores complete; fix_loc final

  // Fused fixup: exact f64 recompute of this block's near-threshold entries from x, w.
  // Writes both (r,c) and (c,r) — twin has the identical bf16-gemm value.
  {
    const int nf = (fix_loc_n < BLK_FIX_CAP) ? fix_loc_n : BLK_FIX_CAP;
    for (int e = wv; e < nf; e += 4) {
      const uint32_t f = fix_loc[e];
      const int r = (int)(f / NROWS), c = (int)(f % NROWS);
      double dot0 = 0, dot1 = 0, nr0 = 0, nr1 = 0, nc0 = 0, nc1 = 0;
      #pragma unroll
      for (int i2 = 0; i2 < DIM / 64; ++i2) {
        const int i = i2 * 64 + lane;
        const double w0 = (double)w[i],              w1 = (double)w[DIM + i];
        const double xr = (double)x[(size_t)r * DIM + i];
        const double xc = (double)x[(size_t)c * DIM + i];
        const double pr0 = xr * w0, pc0 = xc * w0;
        const double pr1 = xr * w1, pc1 = xc * w1;
        dot0 += pr0 * pc0; nr0 += pr0 * pr0; nc0 += pc0 * pc0;
        dot1 += pr1 * pc1; nr1 += pr1 * pr1; nc1 += pc1 * pc1;
      }
      #pragma unroll
      for (int off = 32; off > 0; off >>= 1) {
        dot0 += __shfl_down(dot0, off); nr0 += __shfl_down(nr0, off); nc0 += __shfl_down(nc0, off);
        dot1 += __shfl_down(dot1, off); nr1 += __shfl_down(nr1, off); nc1 += __shfl_down(nc1, off);
      }
      if (lane == 0) {
        const double s0 = dot0 / (fmax(sqrt(nr0), 1e-8) * fmax(sqrt(nc0), 1e-8));
        const double s1 = dot1 / (fmax(sqrt(nr1), 1e-8) * fmax(sqrt(nc1), 1e-8));
        const double sim = 0.5 * (s0 + s1);
        const float res = (sim < (double)THRESH) ? 0.0f : (float)sim;
        out[(size_t)r * NROWS + c] = res;
        out[(size_t)c * NROWS + r] = res;   // twin (self for diagonal entries)
      }
    }
  }

  // Flush per-row count atomics (sparse).
  if (t < 128) {
    if (cntA[t] > 0) atomicAdd(&cnt[rowA + t], cntA[t]);
    if (offd && cntB[t] > 0) atomicAdd(&cnt[rowB + t], cntB[t]);
  }
}

// ---------------- Pass 3: stable top-K fix for (rare) rows with more than K kept
// entries. 8 rows per block (block-uniform early-continue) to cut dispatch count.
__global__ __launch_bounds__(256) void topk_fix(float* __restrict__ out,
                                                const int* __restrict__ cnt,
                                                const int* __restrict__ Kp) {
  const int K = Kp[0];
  __shared__ float vals[TOPK_CAP];
  __shared__ int   idxs[TOPK_CAP];
  __shared__ int   num;
  for (int rr = 0; rr < 8; ++rr) {
    const int row = blockIdx.x * 8 + rr;
    if (cnt[row] <= K) continue;   // block-uniform; common case

    if (threadIdx.x == 0) num = 0;
    __syncthreads();
    for (int j = threadIdx.x; j < NROWS; j += 256) {
      const float v = out[(size_t)row * NROWS + j];
      if (v != 0.0f) {
        const int p = atomicAdd(&num, 1);
        if (p < TOPK_CAP) { vals[p] = v; idxs[p] = j; }
      }
    }
    __syncthreads();
    const int c = (num < TOPK_CAP) ? num : TOPK_CAP;
    // Stable rank = #{q : v_q > v_p or (v_q == v_p and idx_q < idx_p)}; keep rank < K.
    for (int p = threadIdx.x; p < c; p += 256) {
      const float v = vals[p];
      const int  id = idxs[p];
      int rank = 0;
      for (int q = 0; q < c; ++q) {
        const float u = vals[q];
        rank += (u > v) || (u == v && idxs[q] < id);
      }
      if (rank >= K) out[(size_t)row * NROWS + id] = 0.0f;
    }
    __syncthreads();   // vals/idxs/num free before next triggered row
  }
}

extern "C" void kernel_launch(void* const* d_in, const int* in_sizes, int n_in,
                              void* d_out, int out_size, void* d_ws, size_t ws_size,
                              hipStream_t stream) {
  const float* x  = (const float*)d_in[0];
  const float* w  = (const float*)d_in[1];
  const int*   Kp = (const int*)d_in[2];
  float* out = (float*)d_out;

  char* ws = (char*)d_ws;
  ushort* z   = (ushort*)ws;                            // 8 MB
  int*    cnt = (int*)(ws + (size_t)NROWS * KDIM * 2);  // 32 KB

  prep_k<<<NROWS / 4, 256, 0, stream>>>(x, w, z, cnt);      // wave-per-row
  sim_gemm<<<2080, 256, 0, stream>>>(z, x, w, out, cnt);    // 64*65/2 upper-tri blocks
  topk_fix<<<NROWS / 8, 256, 0, stream>>>(out, cnt, Kp);    // 8 rows/block
}